// Round 17
// baseline (355.790 us; speedup 1.0000x reference)
//
#include <hip/hip_runtime.h>
#include <hip/hip_cooperative_groups.h>
#include <math.h>

namespace cg = cooperative_groups;

#define NN 50000
#define NE 600000
#define HID 128
#define NG 64
#define CAP 48    // bucket capacity: Poisson(12) max-degree ~28; P(overflow)<1e-15
#define ASTRH 136 // LDS A-tile row stride in halves (272B): frag reads <=2-way
#define NBIN 196  // coarse bins: dst>>8, ceil(50000/256)
#define CHUNK 2344 // edges per hist/scatter slice: ceil(600000/256)
#define TR 64     // MLP tile rows
#define CSRG 492  // k_csr grid: 236 prep-role + 256 hist/scatter-slice blocks

using half8v = __attribute__((ext_vector_type(8))) _Float16;
using half4v = __attribute__((ext_vector_type(4))) _Float16;
using half2v = __attribute__((ext_vector_type(2))) _Float16;
using f32x4  = __attribute__((ext_vector_type(4))) float;

__device__ __forceinline__ float unpack_w(unsigned p) {
  return (float)__builtin_bit_cast(_Float16, (unsigned short)(p & 0xffffu));
}

// ---- Cooperative CSR builder: prep | hist || scatter || binfill in ONE launch.
// Phase H: blocks [0,196) pos boundaries; [196,204) zero gsum+ticket;
//          [204,236) f32->f16 weight cast; [236,492) LDS bin histogram.
// Phase S: blocks [236,492) scatter slice (hb = b-236) with LDS cursors.
// Phase B: blocks [0,196) binfill bin b with LDS cursors.
// Zero global atomics; phases use disjoint block ranges.
__global__ void k_csr(const int* __restrict__ batch, float* __restrict__ gsum,
                      int* __restrict__ pos, int* __restrict__ ticket,
                      const float* __restrict__ W1a, const float* __restrict__ W1b,
                      const float* __restrict__ W2a, const float* __restrict__ W2b,
                      _Float16* __restrict__ whi,
                      const int* __restrict__ src, const int* __restrict__ dst,
                      const float* __restrict__ ew, int* __restrict__ hist,
                      int* __restrict__ gbinbase, int2* __restrict__ part,
                      unsigned* __restrict__ bkt, int* __restrict__ deg) {
  cg::grid_group grid = cg::this_grid();
  __shared__ int lh[NBIN];
  __shared__ int ps[256];
  __shared__ int cur[256];
  int b = blockIdx.x, t = threadIdx.x;

  // ---------------- Phase H ----------------
  if (b < 196) {
    int i = b * 256 + t;
    if (i < NN) {
      int bb = batch[i];
      if (i == 0) {
        for (int g = 0; g <= bb; ++g) pos[g] = 0;
      } else {
        int bp = batch[i - 1];
        for (int g = bp + 1; g <= bb; ++g) pos[g] = i;
      }
      if (i == NN - 1) {
        for (int g = bb + 1; g <= NG; ++g) pos[g] = NN;
      }
    }
  } else if (b < 204) {
    int i = (b - 196) * 256 + t;
    if (i < 2048) reinterpret_cast<float4*>(gsum)[i] = make_float4(0.f, 0.f, 0.f, 0.f);
    if (b == 196 && t == 0) *ticket = 0;
  } else if (b < 236) {
    int tid = (b - 204) * 256 + t;  // 0..8191
    int m = tid >> 11;
    const float* W = (m == 0) ? W1a : (m == 1) ? W1b : (m == 2) ? W2a : W2b;
    int rem = tid & 2047;
    int kt = rem >> 9;
    int fj = (rem >> 6) & 7;
    int l = rem & 63;
    int col = fj * 16 + (l & 15);
    int kbase = kt * 32 + (l >> 4) * 8;
    size_t obase = (size_t)m * 16384 + (size_t)(((kt * 8 + fj) * 64 + l)) * 8;
#pragma unroll
    for (int j = 0; j < 8; ++j) {
      whi[obase + j] = (_Float16)W[(size_t)(kbase + j) * HID + col];
    }
  } else {
    int hb = b - 236;  // 0..255
    if (t < NBIN) lh[t] = 0;
    __syncthreads();
    int lo = hb * CHUNK, hi = min(lo + CHUNK, NE);
    for (int e = lo + t; e < hi; e += 256) atomicAdd(&lh[dst[e] >> 8], 1);
    __syncthreads();
    if (t < NBIN) hist[t * 256 + hb] = lh[t];
  }
  grid.sync();

  // ---------------- Phase S (blocks 236..491) ----------------
  if (b >= 236) {
    int hb = b - 236;
    int sum0 = 0, T = 0;
    if (t < NBIN) {
      const int* row = &hist[t * 256];
#pragma unroll 4
      for (int i = 0; i < 256; ++i) {
        int v = row[i];
        T += v;
        sum0 += (i < hb) ? v : 0;
      }
    }
    ps[t] = T;
    __syncthreads();
    for (int d = 1; d < 256; d <<= 1) {
      int u = (t >= d) ? ps[t - d] : 0;
      __syncthreads();
      ps[t] += u;
      __syncthreads();
    }
    if (t < NBIN) {
      int ebase = ps[t] - T;
      cur[t] = ebase + sum0;
      if (hb == 0) gbinbase[t] = ebase;
    }
    if (hb == 0 && t == 0) gbinbase[NBIN] = NE;
    __syncthreads();
    int lo = hb * CHUNK, hi = min(lo + CHUNK, NE);
    for (int e = lo + t; e < hi; e += 256) {
      int d0 = dst[e];
      int p = atomicAdd(&cur[d0 >> 8], 1);  // LDS atomic
      _Float16 w = (_Float16)ew[e];
      unsigned wb = (unsigned)__builtin_bit_cast(unsigned short, w);
      part[p] = make_int2(src[e], ((d0 & 255) << 16) | (int)wb);
    }
  }
  grid.sync();

  // ---------------- Phase B (blocks 0..195) ----------------
  if (b < NBIN) {
    cur[t] = 0;
    __syncthreads();
    int lo = gbinbase[b], hi = gbinbase[b + 1];
    for (int e = lo + t; e < hi; e += 256) {
      int2 q = part[e];
      int dl = q.y >> 16;
      int p = atomicAdd(&cur[dl], 1);  // LDS atomic
      if (p < CAP)
        bkt[(size_t)((b << 8) + dl) * CAP + p] =
            ((unsigned)q.x << 16) | ((unsigned)q.y & 0xffffu);
    }
    __syncthreads();
    int node = (b << 8) + t;
    if (node < NN) deg[node] = cur[t];
  }
}

// ---------------- Layer 1 aggregation (rank-1: scalars only), f16 out ----------
__global__ void k_layer1(const float* __restrict__ nw, const unsigned* __restrict__ bkt,
                         const int* __restrict__ deg,
                         const float* __restrict__ Wn, const float* __restrict__ bn,
                         const float* __restrict__ We, const float* __restrict__ be,
                         _Float16* __restrict__ h) {
  int wave = threadIdx.x >> 6;
  int lane = threadIdx.x & 63;
  int node = blockIdx.x * 4 + wave;
  if (node >= NN) return;
  int c = lane * 2;
  float wn0 = Wn[c], wn1 = Wn[c + 1];
  float we0 = We[c], we1 = We[c + 1];
  float bn0 = bn[c], bn1 = bn[c + 1];
  float cb0 = bn0 + be[c], cb1 = bn1 + be[c + 1];
  float ai = nw[node];
  float acc0 = fmaf(ai, wn0, bn0);
  float acc1 = fmaf(ai, wn1, bn1);
  int k0 = node * CAP;
  int cnt = min(deg[node], CAP);
  int k = 0;
  for (; k + 4 <= cnt; k += 4) {
    uint4 q = *reinterpret_cast<const uint4*>(&bkt[k0 + k]);
    float a0 = nw[q.x >> 16], a1 = nw[q.y >> 16];
    float a2 = nw[q.z >> 16], a3 = nw[q.w >> 16];
    float e0 = unpack_w(q.x), e1 = unpack_w(q.y);
    float e2 = unpack_w(q.z), e3 = unpack_w(q.w);
    acc0 += fmaxf(fmaf(a0, wn0, fmaf(e0, we0, cb0)), 0.f);
    acc1 += fmaxf(fmaf(a0, wn1, fmaf(e0, we1, cb1)), 0.f);
    acc0 += fmaxf(fmaf(a1, wn0, fmaf(e1, we0, cb0)), 0.f);
    acc1 += fmaxf(fmaf(a1, wn1, fmaf(e1, we1, cb1)), 0.f);
    acc0 += fmaxf(fmaf(a2, wn0, fmaf(e2, we0, cb0)), 0.f);
    acc1 += fmaxf(fmaf(a2, wn1, fmaf(e2, we1, cb1)), 0.f);
    acc0 += fmaxf(fmaf(a3, wn0, fmaf(e3, we0, cb0)), 0.f);
    acc1 += fmaxf(fmaf(a3, wn1, fmaf(e3, we1, cb1)), 0.f);
  }
  for (; k < cnt; ++k) {
    unsigned p = bkt[k0 + k];
    float a = nw[p >> 16];
    float b = unpack_w(p);
    acc0 += fmaxf(fmaf(a, wn0, fmaf(b, we0, cb0)), 0.f);
    acc1 += fmaxf(fmaf(a, wn1, fmaf(b, we1, cb1)), 0.f);
  }
  half2v o; o[0] = (_Float16)acc0; o[1] = (_Float16)acc1;
  *reinterpret_cast<half2v*>(&h[(size_t)node * HID + c]) = o;
}

// ---------------- Layer 2 aggregation: node-paired gathers (BW-bound floor) ----
__global__ void k_layer2(const _Float16* __restrict__ x1, const unsigned* __restrict__ bkt,
                         const int* __restrict__ deg,
                         const float* __restrict__ We, const float* __restrict__ be,
                         _Float16* __restrict__ h) {
  int wave = threadIdx.x >> 6;
  int l = threadIdx.x & 63;
  int half = l >> 5;
  int lane32 = l & 31;
  int node = blockIdx.x * 8 + wave * 2 + half;  // grid 6250 * 8 = NN exactly
  int c = lane32 * 4;
  float4 w4 = *reinterpret_cast<const float4*>(&We[c]);
  float4 b4 = *reinterpret_cast<const float4*>(&be[c]);
  half4v xs = *reinterpret_cast<const half4v*>(&x1[(size_t)node * HID + c]);
  float acc0 = (float)xs[0], acc1 = (float)xs[1];
  float acc2 = (float)xs[2], acc3 = (float)xs[3];
  int cnt = min(deg[node], CAP);
  int cntO = __shfl_xor(cnt, 32);
  int kmax = max(cnt, cntO);  // wave-uniform
  int k0 = node * CAP;

  for (int k = 0; k < kmax; k += 8) {
    uint4 qa = *reinterpret_cast<const uint4*>(&bkt[k0 + k]);
    uint4 qb = *reinterpret_cast<const uint4*>(&bkt[k0 + k + 4]);
    unsigned qs[8] = {qa.x, qa.y, qa.z, qa.w, qb.x, qb.y, qb.z, qb.w};
    half4v r[8];
#pragma unroll
    for (int i = 0; i < 8; ++i) {
      int s = min((int)(qs[i] >> 16), NN - 1);
      r[i] = *reinterpret_cast<const half4v*>(&x1[(size_t)s * HID + c]);
    }
#pragma unroll
    for (int i = 0; i < 8; ++i) {
      bool v = (k + i) < cnt;
      float e = unpack_w(qs[i]);
      float m0 = fmaxf((float)r[i][0] + fmaf(e, w4.x, b4.x), 0.f);
      float m1 = fmaxf((float)r[i][1] + fmaf(e, w4.y, b4.y), 0.f);
      float m2 = fmaxf((float)r[i][2] + fmaf(e, w4.z, b4.z), 0.f);
      float m3 = fmaxf((float)r[i][3] + fmaf(e, w4.w, b4.w), 0.f);
      acc0 += v ? m0 : 0.f;
      acc1 += v ? m1 : 0.f;
      acc2 += v ? m2 : 0.f;
      acc3 += v ? m3 : 0.f;
    }
  }
  half4v o;
  o[0] = (_Float16)acc0; o[1] = (_Float16)acc1;
  o[2] = (_Float16)acc2; o[3] = (_Float16)acc3;
  *reinterpret_cast<half4v*>(&h[(size_t)node * HID + c]) = o;
}

// ---------------- MFMA MLP pair: Y = relu(leaky(X@Wa+ba)@Wb+bb) ----------------
// 64-row tiles -> 782 blocks (3.05/CU), LDS 17.7KB. Wave owns 16 rows x 128 cols.
// POOL=1 additionally: run-length pooled atomics into gsum, then the LAST block
// (device ticket + threadfence) computes the pooled-MLP head + sigmoid in-place.
template <int POOL>
__global__ __launch_bounds__(256, 6) void k_mlp(
    const _Float16* __restrict__ X,
    const _Float16* __restrict__ Wah, const float* __restrict__ ba,
    const _Float16* __restrict__ Wbh, const float* __restrict__ bb,
    _Float16* __restrict__ Y,
    const int* __restrict__ batch, float* __restrict__ gsum,
    int* __restrict__ ticket, const int* __restrict__ pos,
    const float* __restrict__ Wm1, const float* __restrict__ bm1,
    const float* __restrict__ Wm2, const float* __restrict__ bm2,
    float* __restrict__ out) {
  extern __shared__ char smem_raw[];
  _Float16* Ah = (_Float16*)smem_raw;
  int* sB = (int*)(smem_raw + TR * ASTRH * 2);
  const int tid = threadIdx.x;
  const int l = tid & 63;
  const int wrow = (tid >> 6) * 16;
  const int rowBase = blockIdx.x * TR;

  if (POOL && tid < TR) sB[tid] = batch[min(rowBase + tid, NN - 1)];

  {
    int rr = tid >> 4;         // 0..15
    int c0 = (tid & 15) * 8;   // 0..120
#pragma unroll
    for (int p = 0; p < 4; ++p) {
      int r = p * 16 + rr;
      int srcRow = min(rowBase + r, NN - 1);
      half8v v = *reinterpret_cast<const half8v*>(&X[(size_t)srcRow * HID + c0]);
      *reinterpret_cast<half8v*>(&Ah[r * ASTRH + c0]) = v;
    }
  }
  __syncthreads();

  const int arow0 = wrow + (l & 15);
  const int kgrp = (l >> 4) * 8;
  const int lcol = l & 15;

  f32x4 acc[8];
#pragma unroll
  for (int j = 0; j < 8; ++j) acc[j] = f32x4{0.f, 0.f, 0.f, 0.f};

#pragma unroll
  for (int ks = 0; ks < 4; ++ks) {
    half8v a0 = *reinterpret_cast<const half8v*>(&Ah[arow0 * ASTRH + ks * 32 + kgrp]);
    const _Float16* wbh = &Wah[(size_t)((ks * 8) * 64 + l) * 8];
#pragma unroll
    for (int fj = 0; fj < 8; ++fj) {
      half8v bh = *reinterpret_cast<const half8v*>(wbh + fj * 512);
      acc[fj] = __builtin_amdgcn_mfma_f32_16x16x32_f16(a0, bh, acc[fj], 0, 0, 0);
    }
  }

  {
    float bal[8];
#pragma unroll
    for (int fj = 0; fj < 8; ++fj) bal[fj] = ba[fj * 16 + lcol];
    int rbase = wrow + ((l >> 4) << 2);
#pragma unroll
    for (int fj = 0; fj < 8; ++fj) {
#pragma unroll
      for (int r = 0; r < 4; ++r) {
        float v = acc[fj][r] + bal[fj];
        v = (v > 0.f) ? v : 0.01f * v;
        Ah[(rbase + r) * ASTRH + fj * 16 + lcol] = (_Float16)v;
      }
    }
  }

  f32x4 acc2[8];
#pragma unroll
  for (int j = 0; j < 8; ++j) acc2[j] = f32x4{0.f, 0.f, 0.f, 0.f};

#pragma unroll
  for (int ks = 0; ks < 4; ++ks) {
    half8v a0 = *reinterpret_cast<const half8v*>(&Ah[arow0 * ASTRH + ks * 32 + kgrp]);
    const _Float16* wbh = &Wbh[(size_t)((ks * 8) * 64 + l) * 8];
#pragma unroll
    for (int fj = 0; fj < 8; ++fj) {
      half8v bh = *reinterpret_cast<const half8v*>(wbh + fj * 512);
      acc2[fj] = __builtin_amdgcn_mfma_f32_16x16x32_f16(a0, bh, acc2[fj], 0, 0, 0);
    }
  }

  float bbl[8];
#pragma unroll
  for (int fj = 0; fj < 8; ++fj) bbl[fj] = bb[fj * 16 + lcol];
  const int rbase = wrow + ((l >> 4) << 2);

  if (!POOL) {
#pragma unroll
    for (int fj = 0; fj < 8; ++fj) {
#pragma unroll
      for (int r = 0; r < 4; ++r) {
        int row = rowBase + rbase + r;
        if (row < NN)
          Y[(size_t)row * HID + fj * 16 + lcol] =
              (_Float16)fmaxf(acc2[fj][r] + bbl[fj], 0.f);
      }
    }
  } else {
    __syncthreads();
    _Float16* sPh = (_Float16*)smem_raw;
#pragma unroll
    for (int fj = 0; fj < 8; ++fj) {
#pragma unroll
      for (int r = 0; r < 4; ++r) {
        bool ok = (rowBase + rbase + r) < NN;
        float z = fmaxf(acc2[fj][r] + bbl[fj], 0.f);
        sPh[(rbase + r) * 132 + fj * 16 + lcol] = (_Float16)(ok ? z : 0.f);
      }
    }
    __syncthreads();
    if (tid < HID) {
      int cur = sB[0];
      float run = 0.f;
      for (int r = 0; r < TR; ++r) {
        int g = sB[r];
        if (g != cur) {
          atomicAdd(&gsum[cur * HID + tid], run);
          run = 0.f; cur = g;
        }
        run += (float)sPh[r * 132 + tid];
      }
      atomicAdd(&gsum[cur * HID + tid], run);
    }
    __syncthreads();

    // ---- last-block final: pooled MLP -> sigmoid ----
    __shared__ int isLast;
    __shared__ float invc[NG];
    __shared__ float red2[NG];
    if (tid == 0) {
      __threadfence();
      int tk = atomicAdd(ticket, 1);
      isLast = (tk == (int)gridDim.x - 1);
    }
    __syncthreads();
    if (!isLast) return;
    __threadfence();  // acquire: all gsum atomics now visible
    if (tid < NG) {
      invc[tid] = 1.f / fmaxf((float)(pos[tid + 1] - pos[tid]), 1.f);
      red2[tid] = 0.f;
    }
    __syncthreads();
    int kk = tid & 127;
    int gp = tid >> 7;
    float wm2k = Wm2[kk];
    for (int i = 0; i < 32; ++i) {
      int g = 2 * i + gp;
      float dot = 0.f;
      for (int j = 0; j < HID; ++j)
        dot = fmaf(gsum[g * HID + j], Wm1[j * HID + kk], dot);
      float z = fmaf(dot, invc[g], bm1[kk]);
      z = (z > 0.f) ? z : 0.01f * z;
      float v = z * wm2k;
#pragma unroll
      for (int off = 32; off; off >>= 1) v += __shfl_xor(v, off);
      if ((tid & 63) == 0) atomicAdd(&red2[g], v);  // LDS atomic, 2 per graph
    }
    __syncthreads();
    if (tid < NG) out[tid] = 1.f / (1.f + expf(-(red2[tid] + bm2[0])));
  }
}

extern "C" void kernel_launch(void* const* d_in, const int* in_sizes, int n_in,
                              void* d_out, int out_size, void* d_ws, size_t ws_size,
                              hipStream_t stream) {
  const float* nw = (const float*)d_in[0];
  const float* ew = (const float*)d_in[1];
  const int* ei = (const int*)d_in[2];
  const int* srcp = ei;
  const int* dstp = ei + NE;
  const int* batch = (const int*)d_in[3];
  const float* Wn = (const float*)d_in[4];
  const float* bn = (const float*)d_in[5];
  const float* We = (const float*)d_in[6];
  const float* be = (const float*)d_in[7];
  const float* W1a = (const float*)d_in[8];
  const float* b1a = (const float*)d_in[9];
  const float* W1b = (const float*)d_in[10];
  const float* b1b = (const float*)d_in[11];
  const float* W2a = (const float*)d_in[12];
  const float* b2a = (const float*)d_in[13];
  const float* W2b = (const float*)d_in[14];
  const float* b2b = (const float*)d_in[15];
  const float* Wm1 = (const float*)d_in[16];
  const float* bm1 = (const float*)d_in[17];
  const float* Wm2 = (const float*)d_in[18];
  const float* bm2 = (const float*)d_in[19];
  float* out = (float*)d_out;

  char* ws = (char*)d_ws;
  size_t o = 0;
  auto alloc = [&](size_t b) {
    size_t p = o;
    o += (b + 255) & ~(size_t)255;
    return p;
  };
  size_t deg_o = alloc(NN * 4);                 // written by binfill phase
  size_t gsum_o = alloc((size_t)NG * HID * 4);
  size_t pos_o = alloc((NG + 1) * 4);
  size_t tick_o = alloc(256);
  size_t hist_o = alloc((size_t)NBIN * 256 * 4);
  size_t gbb_o = alloc((NBIN + 1) * 4);
  size_t part_o = alloc((size_t)NE * 8);        // bin-partitioned edges
  size_t bkt_o = alloc((size_t)NN * CAP * 4);   // packed-u32 bucketed CSR
  size_t h1_o = alloc((size_t)NN * HID * 2);
  size_t x1_o = alloc((size_t)NN * HID * 2);
  size_t h2_o = alloc((size_t)NN * HID * 2);
  size_t whi_o = alloc((size_t)4 * 16384 * 2);  // f16, 4 matrices frag-linear

  int* deg = (int*)(ws + deg_o);
  float* gsum = (float*)(ws + gsum_o);
  int* pos = (int*)(ws + pos_o);
  int* ticket = (int*)(ws + tick_o);
  int* hist = (int*)(ws + hist_o);
  int* gbinbase = (int*)(ws + gbb_o);
  int2* part = (int2*)(ws + part_o);
  unsigned* bkt = (unsigned*)(ws + bkt_o);
  _Float16* h1 = (_Float16*)(ws + h1_o);
  _Float16* x1h = (_Float16*)(ws + x1_o);
  _Float16* h2 = (_Float16*)(ws + h2_o);
  _Float16* whi = (_Float16*)(ws + whi_o);

  // 5 dispatches (was 8): coop CSR build, layer1, mlp0, layer2, mlp1+final
  {
    void* args[] = {(void*)&batch, (void*)&gsum, (void*)&pos, (void*)&ticket,
                    (void*)&W1a, (void*)&W1b, (void*)&W2a, (void*)&W2b,
                    (void*)&whi, (void*)&srcp, (void*)&dstp, (void*)&ew,
                    (void*)&hist, (void*)&gbinbase, (void*)&part,
                    (void*)&bkt, (void*)&deg};
    hipLaunchCooperativeKernel(reinterpret_cast<const void*>(&k_csr),
                               dim3(CSRG), dim3(256), args, 0, stream);
  }

  k_layer1<<<NN / 4, 256, 0, stream>>>(nw, bkt, deg, Wn, bn, We, be, h1);

  size_t smem = (size_t)TR * ASTRH * 2 + TR * 4;  // 17,664 B
  const int mlpBlocks = (NN + TR - 1) / TR;  // 782
  k_mlp<0><<<mlpBlocks, 256, smem, stream>>>(h1, whi, b1a, whi + 16384, b1b,
                                             x1h, nullptr, nullptr, nullptr,
                                             nullptr, nullptr, nullptr, nullptr,
                                             nullptr, nullptr);

  k_layer2<<<NN / 8, 256, 0, stream>>>(x1h, bkt, deg, We, be, h2);

  k_mlp<1><<<mlpBlocks, 256, smem, stream>>>(h2, whi + 2 * 16384, b2a,
                                             whi + 3 * 16384, b2b,
                                             nullptr, batch, gsum,
                                             ticket, pos, Wm1, bm1, Wm2, bm2, out);
}

// Round 18
// 132.119 us; speedup vs baseline: 2.6930x; 2.6930x over previous
//
#include <hip/hip_runtime.h>
#include <math.h>

#define NN 50000
#define NE 600000
#define HID 128
#define NG 64
#define CAP 48    // bucket capacity: Poisson(12) max-degree ~28; P(overflow)<1e-15
#define ASTRH 136 // LDS A-tile row stride in halves (272B): frag reads <=2-way
#define NBIN 196  // coarse bins: dst>>8, ceil(50000/256)
#define CHUNK 2344 // edges per hist/scatter block: ceil(600000/256)
#define TR 64     // MLP tile rows

using half8v = __attribute__((ext_vector_type(8))) _Float16;
using half4v = __attribute__((ext_vector_type(4))) _Float16;
using half2v = __attribute__((ext_vector_type(2))) _Float16;
using f32x4  = __attribute__((ext_vector_type(4))) float;

__device__ __forceinline__ float unpack_w(unsigned p) {
  return (float)__builtin_bit_cast(_Float16, (unsigned short)(p & 0xffffu));
}

// ---- Fused prep: pos | zero gsum | weight cast | per-block bin histogram ----
__global__ void k_prep(const int* __restrict__ batch, float* __restrict__ gsum,
                       int* __restrict__ pos,
                       const float* __restrict__ W1a, const float* __restrict__ W1b,
                       const float* __restrict__ W2a, const float* __restrict__ W2b,
                       _Float16* __restrict__ whi,
                       const int* __restrict__ dst, int* __restrict__ hist) {
  __shared__ int lh[NBIN];
  int b = blockIdx.x, t = threadIdx.x;
  if (b < 196) {
    int i = b * 256 + t;
    if (i < NN) {
      int bb = batch[i];
      if (i == 0) {
        for (int g = 0; g <= bb; ++g) pos[g] = 0;
      } else {
        int bp = batch[i - 1];
        for (int g = bp + 1; g <= bb; ++g) pos[g] = i;
      }
      if (i == NN - 1) {
        for (int g = bb + 1; g <= NG; ++g) pos[g] = NN;
      }
    }
  } else if (b < 204) {
    int i = (b - 196) * 256 + t;
    if (i < 2048) reinterpret_cast<float4*>(gsum)[i] = make_float4(0.f, 0.f, 0.f, 0.f);
  } else if (b < 236) {
    int tid = (b - 204) * 256 + t;  // 0..8191
    int m = tid >> 11;
    const float* W = (m == 0) ? W1a : (m == 1) ? W1b : (m == 2) ? W2a : W2b;
    int rem = tid & 2047;
    int kt = rem >> 9;
    int fj = (rem >> 6) & 7;
    int l = rem & 63;
    int col = fj * 16 + (l & 15);
    int kbase = kt * 32 + (l >> 4) * 8;
    size_t obase = (size_t)m * 16384 + (size_t)(((kt * 8 + fj) * 64 + l)) * 8;
#pragma unroll
    for (int j = 0; j < 8; ++j) {
      whi[obase + j] = (_Float16)W[(size_t)(kbase + j) * HID + col];
    }
  } else {
    int hb = b - 236;  // 0..255
    if (t < NBIN) lh[t] = 0;
    __syncthreads();
    int lo = hb * CHUNK, hi = min(lo + CHUNK, NE);
    for (int e = lo + t; e < hi; e += 256) atomicAdd(&lh[dst[e] >> 8], 1);
    __syncthreads();
    if (t < NBIN) hist[t * 256 + hb] = lh[t];
  }
}

// ---- Scatter: partition edges by bin (dst>>8). ZERO global atomics. ----
__global__ void k_scatter(const int* __restrict__ src, const int* __restrict__ dst,
                          const float* __restrict__ ew, const int* __restrict__ hist,
                          int* __restrict__ gbinbase, int2* __restrict__ part) {
  __shared__ int ps[256];
  __shared__ int cur[NBIN];
  int b = blockIdx.x, t = threadIdx.x;
  int sum0 = 0, T = 0;
  if (t < NBIN) {
    const int* row = &hist[t * 256];
#pragma unroll 4
    for (int i = 0; i < 256; ++i) {
      int v = row[i];
      T += v;
      sum0 += (i < b) ? v : 0;
    }
  }
  ps[t] = T;
  __syncthreads();
  for (int d = 1; d < 256; d <<= 1) {
    int u = (t >= d) ? ps[t - d] : 0;
    __syncthreads();
    ps[t] += u;
    __syncthreads();
  }
  if (t < NBIN) {
    int ebase = ps[t] - T;
    cur[t] = ebase + sum0;
    if (b == 0) gbinbase[t] = ebase;
  }
  if (b == 0 && t == 0) gbinbase[NBIN] = NE;
  __syncthreads();
  int lo = b * CHUNK, hi = min(lo + CHUNK, NE);
  for (int e = lo + t; e < hi; e += 256) {
    int d0 = dst[e];
    int p = atomicAdd(&cur[d0 >> 8], 1);  // LDS atomic
    _Float16 w = (_Float16)ew[e];
    unsigned wb = (unsigned)__builtin_bit_cast(unsigned short, w);
    part[p] = make_int2(src[e], ((d0 & 255) << 16) | (int)wb);
  }
}

// ---- Binfill: bin j's contiguous edges -> per-dst bucket slots (LDS cursors).
__global__ void k_binfill(const int2* __restrict__ part, const int* __restrict__ gbinbase,
                          unsigned* __restrict__ bkt, int* __restrict__ deg) {
  __shared__ int cur[256];
  int j = blockIdx.x, t = threadIdx.x;
  cur[t] = 0;
  __syncthreads();
  int lo = gbinbase[j], hi = gbinbase[j + 1];
  for (int e = lo + t; e < hi; e += 256) {
    int2 q = part[e];
    int dl = q.y >> 16;
    int p = atomicAdd(&cur[dl], 1);  // LDS atomic
    if (p < CAP)
      bkt[(size_t)((j << 8) + dl) * CAP + p] =
          ((unsigned)q.x << 16) | ((unsigned)q.y & 0xffffu);
  }
  __syncthreads();
  int node = (j << 8) + t;
  if (node < NN) deg[node] = cur[t];
}

// ---------------- Layer 1 aggregation (rank-1: scalars only), f16 out ----------
__global__ void k_layer1(const float* __restrict__ nw, const unsigned* __restrict__ bkt,
                         const int* __restrict__ deg,
                         const float* __restrict__ Wn, const float* __restrict__ bn,
                         const float* __restrict__ We, const float* __restrict__ be,
                         _Float16* __restrict__ h) {
  int wave = threadIdx.x >> 6;
  int lane = threadIdx.x & 63;
  int node = blockIdx.x * 4 + wave;
  if (node >= NN) return;
  int c = lane * 2;
  float wn0 = Wn[c], wn1 = Wn[c + 1];
  float we0 = We[c], we1 = We[c + 1];
  float bn0 = bn[c], bn1 = bn[c + 1];
  float cb0 = bn0 + be[c], cb1 = bn1 + be[c + 1];
  float ai = nw[node];
  float acc0 = fmaf(ai, wn0, bn0);
  float acc1 = fmaf(ai, wn1, bn1);
  int k0 = node * CAP;
  int cnt = min(deg[node], CAP);
  int k = 0;
  for (; k + 4 <= cnt; k += 4) {
    uint4 q = *reinterpret_cast<const uint4*>(&bkt[k0 + k]);
    float a0 = nw[q.x >> 16], a1 = nw[q.y >> 16];
    float a2 = nw[q.z >> 16], a3 = nw[q.w >> 16];
    float e0 = unpack_w(q.x), e1 = unpack_w(q.y);
    float e2 = unpack_w(q.z), e3 = unpack_w(q.w);
    acc0 += fmaxf(fmaf(a0, wn0, fmaf(e0, we0, cb0)), 0.f);
    acc1 += fmaxf(fmaf(a0, wn1, fmaf(e0, we1, cb1)), 0.f);
    acc0 += fmaxf(fmaf(a1, wn0, fmaf(e1, we0, cb0)), 0.f);
    acc1 += fmaxf(fmaf(a1, wn1, fmaf(e1, we1, cb1)), 0.f);
    acc0 += fmaxf(fmaf(a2, wn0, fmaf(e2, we0, cb0)), 0.f);
    acc1 += fmaxf(fmaf(a2, wn1, fmaf(e2, we1, cb1)), 0.f);
    acc0 += fmaxf(fmaf(a3, wn0, fmaf(e3, we0, cb0)), 0.f);
    acc1 += fmaxf(fmaf(a3, wn1, fmaf(e3, we1, cb1)), 0.f);
  }
  for (; k < cnt; ++k) {
    unsigned p = bkt[k0 + k];
    float a = nw[p >> 16];
    float b = unpack_w(p);
    acc0 += fmaxf(fmaf(a, wn0, fmaf(b, we0, cb0)), 0.f);
    acc1 += fmaxf(fmaf(a, wn1, fmaf(b, we1, cb1)), 0.f);
  }
  half2v o; o[0] = (_Float16)acc0; o[1] = (_Float16)acc1;
  *reinterpret_cast<half2v*>(&h[(size_t)node * HID + c]) = o;
}

// ---------------- Layer 2 aggregation: node-paired gathers (BW-bound floor) ----
__global__ void k_layer2(const _Float16* __restrict__ x1, const unsigned* __restrict__ bkt,
                         const int* __restrict__ deg,
                         const float* __restrict__ We, const float* __restrict__ be,
                         _Float16* __restrict__ h) {
  int wave = threadIdx.x >> 6;
  int l = threadIdx.x & 63;
  int half = l >> 5;
  int lane32 = l & 31;
  int node = blockIdx.x * 8 + wave * 2 + half;  // grid 6250 * 8 = NN exactly
  int c = lane32 * 4;
  float4 w4 = *reinterpret_cast<const float4*>(&We[c]);
  float4 b4 = *reinterpret_cast<const float4*>(&be[c]);
  half4v xs = *reinterpret_cast<const half4v*>(&x1[(size_t)node * HID + c]);
  float acc0 = (float)xs[0], acc1 = (float)xs[1];
  float acc2 = (float)xs[2], acc3 = (float)xs[3];
  int cnt = min(deg[node], CAP);
  int cntO = __shfl_xor(cnt, 32);
  int kmax = max(cnt, cntO);  // wave-uniform
  int k0 = node * CAP;

  for (int k = 0; k < kmax; k += 8) {
    uint4 qa = *reinterpret_cast<const uint4*>(&bkt[k0 + k]);
    uint4 qb = *reinterpret_cast<const uint4*>(&bkt[k0 + k + 4]);
    unsigned qs[8] = {qa.x, qa.y, qa.z, qa.w, qb.x, qb.y, qb.z, qb.w};
    half4v r[8];
#pragma unroll
    for (int i = 0; i < 8; ++i) {
      int s = min((int)(qs[i] >> 16), NN - 1);
      r[i] = *reinterpret_cast<const half4v*>(&x1[(size_t)s * HID + c]);
    }
#pragma unroll
    for (int i = 0; i < 8; ++i) {
      bool v = (k + i) < cnt;
      float e = unpack_w(qs[i]);
      float m0 = fmaxf((float)r[i][0] + fmaf(e, w4.x, b4.x), 0.f);
      float m1 = fmaxf((float)r[i][1] + fmaf(e, w4.y, b4.y), 0.f);
      float m2 = fmaxf((float)r[i][2] + fmaf(e, w4.z, b4.z), 0.f);
      float m3 = fmaxf((float)r[i][3] + fmaf(e, w4.w, b4.w), 0.f);
      acc0 += v ? m0 : 0.f;
      acc1 += v ? m1 : 0.f;
      acc2 += v ? m2 : 0.f;
      acc3 += v ? m3 : 0.f;
    }
  }
  half4v o;
  o[0] = (_Float16)acc0; o[1] = (_Float16)acc1;
  o[2] = (_Float16)acc2; o[3] = (_Float16)acc3;
  *reinterpret_cast<half4v*>(&h[(size_t)node * HID + c]) = o;
}

// ---------------- MFMA MLP pair: Y = relu(leaky(X@Wa+ba)@Wb+bb) ----------------
// 64-row tiles -> 782 blocks (3.05/CU), LDS 17.7KB. Wave owns 16 rows x 128 cols.
template <int POOL>
__global__ __launch_bounds__(256, 6) void k_mlp(
    const _Float16* __restrict__ X,
    const _Float16* __restrict__ Wah, const float* __restrict__ ba,
    const _Float16* __restrict__ Wbh, const float* __restrict__ bb,
    _Float16* __restrict__ Y,
    const int* __restrict__ batch, float* __restrict__ gsum) {
  extern __shared__ char smem_raw[];
  _Float16* Ah = (_Float16*)smem_raw;
  int* sB = (int*)(smem_raw + TR * ASTRH * 2);
  const int tid = threadIdx.x;
  const int l = tid & 63;
  const int wrow = (tid >> 6) * 16;
  const int rowBase = blockIdx.x * TR;

  if (POOL && tid < TR) sB[tid] = batch[min(rowBase + tid, NN - 1)];

  {
    int rr = tid >> 4;         // 0..15
    int c0 = (tid & 15) * 8;   // 0..120
#pragma unroll
    for (int p = 0; p < 4; ++p) {
      int r = p * 16 + rr;
      int srcRow = min(rowBase + r, NN - 1);
      half8v v = *reinterpret_cast<const half8v*>(&X[(size_t)srcRow * HID + c0]);
      *reinterpret_cast<half8v*>(&Ah[r * ASTRH + c0]) = v;
    }
  }
  __syncthreads();

  const int arow0 = wrow + (l & 15);
  const int kgrp = (l >> 4) * 8;
  const int lcol = l & 15;

  f32x4 acc[8];
#pragma unroll
  for (int j = 0; j < 8; ++j) acc[j] = f32x4{0.f, 0.f, 0.f, 0.f};

#pragma unroll
  for (int ks = 0; ks < 4; ++ks) {
    half8v a0 = *reinterpret_cast<const half8v*>(&Ah[arow0 * ASTRH + ks * 32 + kgrp]);
    const _Float16* wbh = &Wah[(size_t)((ks * 8) * 64 + l) * 8];
#pragma unroll
    for (int fj = 0; fj < 8; ++fj) {
      half8v bh = *reinterpret_cast<const half8v*>(wbh + fj * 512);
      acc[fj] = __builtin_amdgcn_mfma_f32_16x16x32_f16(a0, bh, acc[fj], 0, 0, 0);
    }
  }

  {
    float bal[8];
#pragma unroll
    for (int fj = 0; fj < 8; ++fj) bal[fj] = ba[fj * 16 + lcol];
    int rbase = wrow + ((l >> 4) << 2);
#pragma unroll
    for (int fj = 0; fj < 8; ++fj) {
#pragma unroll
      for (int r = 0; r < 4; ++r) {
        float v = acc[fj][r] + bal[fj];
        v = (v > 0.f) ? v : 0.01f * v;
        Ah[(rbase + r) * ASTRH + fj * 16 + lcol] = (_Float16)v;
      }
    }
  }

  f32x4 acc2[8];
#pragma unroll
  for (int j = 0; j < 8; ++j) acc2[j] = f32x4{0.f, 0.f, 0.f, 0.f};

#pragma unroll
  for (int ks = 0; ks < 4; ++ks) {
    half8v a0 = *reinterpret_cast<const half8v*>(&Ah[arow0 * ASTRH + ks * 32 + kgrp]);
    const _Float16* wbh = &Wbh[(size_t)((ks * 8) * 64 + l) * 8];
#pragma unroll
    for (int fj = 0; fj < 8; ++fj) {
      half8v bh = *reinterpret_cast<const half8v*>(wbh + fj * 512);
      acc2[fj] = __builtin_amdgcn_mfma_f32_16x16x32_f16(a0, bh, acc2[fj], 0, 0, 0);
    }
  }

  float bbl[8];
#pragma unroll
  for (int fj = 0; fj < 8; ++fj) bbl[fj] = bb[fj * 16 + lcol];
  const int rbase = wrow + ((l >> 4) << 2);

  if (!POOL) {
#pragma unroll
    for (int fj = 0; fj < 8; ++fj) {
#pragma unroll
      for (int r = 0; r < 4; ++r) {
        int row = rowBase + rbase + r;
        if (row < NN)
          Y[(size_t)row * HID + fj * 16 + lcol] =
              (_Float16)fmaxf(acc2[fj][r] + bbl[fj], 0.f);
      }
    }
  } else {
    __syncthreads();
    _Float16* sPh = (_Float16*)smem_raw;
#pragma unroll
    for (int fj = 0; fj < 8; ++fj) {
#pragma unroll
      for (int r = 0; r < 4; ++r) {
        bool ok = (rowBase + rbase + r) < NN;
        float z = fmaxf(acc2[fj][r] + bbl[fj], 0.f);
        sPh[(rbase + r) * 132 + fj * 16 + lcol] = (_Float16)(ok ? z : 0.f);
      }
    }
    __syncthreads();
    if (tid < HID) {
      int cur = sB[0];
      float run = 0.f;
      for (int r = 0; r < TR; ++r) {
        int g = sB[r];
        if (g != cur) {
          atomicAdd(&gsum[cur * HID + tid], run);
          run = 0.f; cur = g;
        }
        run += (float)sPh[r * 132 + tid];
      }
      atomicAdd(&gsum[cur * HID + tid], run);
    }
  }
}

// ---------------- Final: pooled MLP -> sigmoid ----------------
__global__ void k_final(const float* __restrict__ gsum, const int* __restrict__ pos,
                        const float* __restrict__ Wm1, const float* __restrict__ bm1,
                        const float* __restrict__ Wm2, const float* __restrict__ bm2,
                        float* __restrict__ out) {
  __shared__ float sp[HID];
  __shared__ float red[HID];
  int g = blockIdx.x;
  int k = threadIdx.x;  // 128 threads
  float c = fmaxf((float)(pos[g + 1] - pos[g]), 1.f);
  sp[k] = gsum[g * HID + k] / c;
  __syncthreads();
  float dot = 0.f;
  for (int j = 0; j < HID; ++j) dot = fmaf(sp[j], Wm1[j * HID + k], dot);
  float z = dot + bm1[k];
  z = (z > 0.f) ? z : 0.01f * z;
  red[k] = z * Wm2[k];
  __syncthreads();
  for (int s = 64; s > 0; s >>= 1) {
    if (k < s) red[k] += red[k + s];
    __syncthreads();
  }
  if (k == 0) out[g] = 1.f / (1.f + expf(-(red[0] + bm2[0])));
}

extern "C" void kernel_launch(void* const* d_in, const int* in_sizes, int n_in,
                              void* d_out, int out_size, void* d_ws, size_t ws_size,
                              hipStream_t stream) {
  const float* nw = (const float*)d_in[0];
  const float* ew = (const float*)d_in[1];
  const int* ei = (const int*)d_in[2];
  const int* src = ei;
  const int* dst = ei + NE;
  const int* batch = (const int*)d_in[3];
  const float* Wn = (const float*)d_in[4];
  const float* bn = (const float*)d_in[5];
  const float* We = (const float*)d_in[6];
  const float* be = (const float*)d_in[7];
  const float* W1a = (const float*)d_in[8];
  const float* b1a = (const float*)d_in[9];
  const float* W1b = (const float*)d_in[10];
  const float* b1b = (const float*)d_in[11];
  const float* W2a = (const float*)d_in[12];
  const float* b2a = (const float*)d_in[13];
  const float* W2b = (const float*)d_in[14];
  const float* b2b = (const float*)d_in[15];
  const float* Wm1 = (const float*)d_in[16];
  const float* bm1 = (const float*)d_in[17];
  const float* Wm2 = (const float*)d_in[18];
  const float* bm2 = (const float*)d_in[19];
  float* out = (float*)d_out;

  char* ws = (char*)d_ws;
  size_t o = 0;
  auto alloc = [&](size_t b) {
    size_t p = o;
    o += (b + 255) & ~(size_t)255;
    return p;
  };
  size_t deg_o = alloc(NN * 4);                 // written by binfill (no pre-zero)
  size_t gsum_o = alloc((size_t)NG * HID * 4);
  size_t pos_o = alloc((NG + 1) * 4);
  size_t hist_o = alloc((size_t)NBIN * 256 * 4);
  size_t gbb_o = alloc((NBIN + 1) * 4);
  size_t part_o = alloc((size_t)NE * 8);        // bin-partitioned edges
  size_t bkt_o = alloc((size_t)NN * CAP * 4);   // packed-u32 bucketed CSR
  size_t h1_o = alloc((size_t)NN * HID * 2);
  size_t x1_o = alloc((size_t)NN * HID * 2);
  size_t h2_o = alloc((size_t)NN * HID * 2);
  size_t whi_o = alloc((size_t)4 * 16384 * 2);  // f16, 4 matrices frag-linear

  int* deg = (int*)(ws + deg_o);
  float* gsum = (float*)(ws + gsum_o);
  int* pos = (int*)(ws + pos_o);
  int* hist = (int*)(ws + hist_o);
  int* gbinbase = (int*)(ws + gbb_o);
  int2* part = (int2*)(ws + part_o);
  unsigned* bkt = (unsigned*)(ws + bkt_o);
  _Float16* h1 = (_Float16*)(ws + h1_o);
  _Float16* x1h = (_Float16*)(ws + x1_o);
  _Float16* h2 = (_Float16*)(ws + h2_o);
  _Float16* whi = (_Float16*)(ws + whi_o);

  // 8 dispatches, zero global atomics in the CSR build (R16 structure:
  // coop-fusion and last-block-final both measured as large regressions in R17)
  k_prep<<<492, 256, 0, stream>>>(batch, gsum, pos, W1a, W1b, W2a, W2b, whi,
                                  dst, hist);
  k_scatter<<<256, 256, 0, stream>>>(src, dst, ew, hist, gbinbase, part);
  k_binfill<<<NBIN, 256, 0, stream>>>(part, gbinbase, bkt, deg);

  k_layer1<<<NN / 4, 256, 0, stream>>>(nw, bkt, deg, Wn, bn, We, be, h1);

  size_t smem = (size_t)TR * ASTRH * 2 + TR * 4;  // 17,664 B -> up to 6 blocks/CU
  const int mlpBlocks = (NN + TR - 1) / TR;  // 782
  k_mlp<0><<<mlpBlocks, 256, smem, stream>>>(h1, whi, b1a, whi + 16384, b1b,
                                             x1h, nullptr, nullptr);

  k_layer2<<<NN / 8, 256, 0, stream>>>(x1h, bkt, deg, We, be, h2);

  k_mlp<1><<<mlpBlocks, 256, smem, stream>>>(h2, whi + 2 * 16384, b2a,
                                             whi + 3 * 16384, b2b,
                                             nullptr, batch, gsum);

  k_final<<<NG, HID, 0, stream>>>(gsum, pos, Wm1, bm1, Wm2, bm2, out);
}